// Round 6
// baseline (272.143 us; speedup 1.0000x reference)
//
#include <hip/hip_runtime.h>
#include <hip/hip_cooperative_groups.h>
#include <math.h>

// x: (256, 224, 224) f32.  7 blocks per row, per-row counter sync.
#define HW    50176
#define NV4   12544          // float4 per row
#define ROWS  256
#define CPR   7              // blocks per row
#define CF4   1792           // float4 per chunk (= 7 * 256)
#define TPB   256
#define NBLK  (ROWS * CPR)   // 1792 blocks = 7 blocks/CU over 256 CUs

typedef float floatx4 __attribute__((ext_vector_type(4)));

// ws layout (bytes):
//   float  mins [1792] @ 0
//   double sums [1792] @ 8192
//   double sls  [1792] @ 24576
//   int    c1   [256]  @ 40960   (phase-1 arrival counters)
//   int    c2   [256]  @ 41984   (phase-2 arrival counters)
#define WMIN(ws) ((float*)(ws))
#define WSUM(ws) ((double*)((char*)(ws) + 8192))
#define WSL(ws)  ((double*)((char*)(ws) + 24576))
#define WC1(ws)  ((int*)((char*)(ws) + 40960))
#define WC2(ws)  ((int*)((char*)(ws) + 41984))

__device__ __forceinline__ float waveMin(float v) {
#pragma unroll
    for (int o = 32; o > 0; o >>= 1) v = fminf(v, __shfl_down(v, o, 64));
    return v;
}
__device__ __forceinline__ double waveSumD(double v) {
#pragma unroll
    for (int o = 32; o > 0; o >>= 1) v += __shfl_down(v, o, 64);
    return v;
}

__device__ __forceinline__ float digamma_f(float x) {
    float r = 0.0f;
#pragma unroll 6
    for (int i = 0; i < 6; ++i) {
        if (x < 6.0f) { r -= __fdividef(1.0f, x); x += 1.0f; }
    }
    float f = __fdividef(1.0f, x * x);
    float ser = f * (1.0f/12.0f - f * (1.0f/120.0f - f * (1.0f/252.0f - f * (1.0f/240.0f - f * (1.0f/132.0f)))));
    return r + logf(x) - 0.5f * __fdividef(1.0f, x) - ser;
}
__device__ __forceinline__ float trigamma_ref(float x) {
    float z = x + 1.0f, zz = z * z;
    float a = 0.2f - __fdividef(1.0f, 7.0f * zz);
    float b = 1.0f - __fdividef(a, zz);
    float c = 1.0f + __fdividef(b, 3.0f * z);
    float d = 1.0f + __fdividef(c, 2.0f * z);
    return __fdividef(d, z) + __fdividef(1.0f, x * x);
}

// ts = raw row sum of x, tl = row sum of log(x - rmin + 2e-7).  par: {k, invth, c0..c7}
__device__ __forceinline__ void solve_params(double ts, double tl, float rmin, float* par) {
    ts -= (double)HW * ((double)rmin - 2e-7);
    const double meand = ts / (double)HW;
    float s = logf((float)meand) - (float)(tl / (double)HW);

    float s3 = s - 3.0f;
    float rt = sqrtf(s3 * s3 + 24.0f * s);
    float k  = __fdividef(3.0f - s + rt, 12.0f * s) + 1e-7f;
#pragma unroll
    for (int it = 0; it < 10; ++it) {
        float nm = logf(k) - digamma_f(k) - s;
        float dn = __fdividef(1.0f, k) - trigamma_ref(k);
        k -= __fdividef(nm, dn);
    }
    if (k < 1e-7f) k = 1e-7f;   // NaN falls through (np.clip semantics)
    if (k > 18.0f) k = 18.0f;

    const double CH[8] = {676.5203681218851, -1259.1392167224028, 771.3234287776531,
                          -176.6150291621406, 12.507343278686905, -0.13857109526572012,
                          9.984369578019572e-06, 1.5056327351493116e-07};
    double acc = 0.9999999999998099;
#pragma unroll
    for (int i = 0; i < 8; ++i) acc += CH[i] / ((double)k + (double)(i + 1));
    float t = k + 7.5f;
    float g = __expf(fmaf(k + 0.5f, __logf(t), -t)) * 2.50662827463f * (float)acc / k; // Gamma(k)

    par[0] = k;
    par[1] = (float)((double)k / meand);   // 1/theta
    float den = g * k;
    par[2] = __fdividef(1.0f, den);
#pragma unroll
    for (int j = 1; j < 8; ++j) {
        den *= (k + (float)j);
        par[2 + j] = __fdividef(1.0f, den);
    }
}

__device__ __forceinline__ float apply_one(float e, float rmin, float invth,
                                           float kk, const float* c) {
    float xq = (e - rmin + 1e-7f) * invth;
    float p = fmaf(c[7], xq, c[6]);
    p = fmaf(p, xq, c[5]);
    p = fmaf(p, xq, c[4]);
    p = fmaf(p, xq, c[3]);
    p = fmaf(p, xq, c[2]);
    p = fmaf(p, xq, c[1]);
    p = fmaf(p, xq, c[0]);
    float y = __expf(fmaf(kk, __logf(xq), -xq)) * p;
    return isfinite(y) ? y : 0.0f;
}

// ==================== cooperative, counter-synced single pass ====================
__global__ void __launch_bounds__(TPB, 7)
gamma_sync(const float* __restrict__ x, float* __restrict__ out, void* __restrict__ ws) {
    const int bid  = blockIdx.x;
    const int row  = bid / CPR;
    const int chnk = bid - row * CPR;
    const int tid  = threadIdx.x;
    const int wid  = tid >> 6, lane = tid & 63;

    const size_t base = (size_t)row * NV4 + (size_t)chnk * CF4;
    const float4* __restrict__ xr = (const float4*)x + base;

    // chunk in registers: 7 float4 = 28 VGPR
    float4 v[7];
#pragma unroll
    for (int j = 0; j < 7; ++j) v[j] = xr[j * TPB + tid];

    // ---- phase A: chunk min + raw sum ----
    float pmin = INFINITY, psum = 0.0f;
#pragma unroll
    for (int j = 0; j < 7; ++j) {
        pmin = fminf(pmin, fminf(fminf(v[j].x, v[j].y), fminf(v[j].z, v[j].w)));
        psum += (v[j].x + v[j].y) + (v[j].z + v[j].w);
    }
    pmin = waveMin(pmin);
    double dsum = waveSumD((double)psum);

    __shared__ float  smin[4];
    __shared__ double sacc[4];
    __shared__ float  spar[11];          // [0]=rmin, [1]=k, [2]=invth, [3..10]=c
    if (lane == 0) { smin[wid] = pmin; sacc[wid] = dsum; }
    __syncthreads();
    if (tid == 0) {
        float  mm = fminf(fminf(smin[0], smin[1]), fminf(smin[2], smin[3]));
        double ss = (sacc[0] + sacc[1]) + (sacc[2] + sacc[3]);
        __hip_atomic_store(&WMIN(ws)[bid], mm, __ATOMIC_RELAXED, __HIP_MEMORY_SCOPE_AGENT);
        __hip_atomic_store(&WSUM(ws)[bid], ss, __ATOMIC_RELAXED, __HIP_MEMORY_SCOPE_AGENT);
        __hip_atomic_fetch_add(&WC1(ws)[row], 1, __ATOMIC_RELEASE, __HIP_MEMORY_SCOPE_AGENT);
        // spin for all 7 sibling chunks of this row
        while (__hip_atomic_load(&WC1(ws)[row], __ATOMIC_ACQUIRE, __HIP_MEMORY_SCOPE_AGENT) < CPR)
            __builtin_amdgcn_s_sleep(2);
        float rm = INFINITY;
#pragma unroll
        for (int i = 0; i < CPR; ++i)
            rm = fminf(rm, __hip_atomic_load(&WMIN(ws)[row * CPR + i],
                                             __ATOMIC_RELAXED, __HIP_MEMORY_SCOPE_AGENT));
        spar[0] = rm;
    }
    __syncthreads();
    const float rmin = spar[0];

    // ---- phase B: chunk sumlog of (x - rmin + 2e-7) from registers ----
    float psl = 0.0f;
#pragma unroll
    for (int j = 0; j < 7; ++j) {
        psl += (__logf(v[j].x - rmin + 1e-7f + 1e-7f) + __logf(v[j].y - rmin + 1e-7f + 1e-7f))
             + (__logf(v[j].z - rmin + 1e-7f + 1e-7f) + __logf(v[j].w - rmin + 1e-7f + 1e-7f));
    }
    double dsl = waveSumD((double)psl);
    if (lane == 0) sacc[wid] = dsl;
    __syncthreads();
    if (tid == 0) {
        double sl = (sacc[0] + sacc[1]) + (sacc[2] + sacc[3]);
        __hip_atomic_store(&WSL(ws)[bid], sl, __ATOMIC_RELAXED, __HIP_MEMORY_SCOPE_AGENT);
        __hip_atomic_fetch_add(&WC2(ws)[row], 1, __ATOMIC_RELEASE, __HIP_MEMORY_SCOPE_AGENT);
        while (__hip_atomic_load(&WC2(ws)[row], __ATOMIC_ACQUIRE, __HIP_MEMORY_SCOPE_AGENT) < CPR)
            __builtin_amdgcn_s_sleep(2);
        double ts = 0.0, tl = 0.0;
#pragma unroll
        for (int i = 0; i < CPR; ++i) {
            ts += __hip_atomic_load(&WSUM(ws)[row * CPR + i], __ATOMIC_RELAXED, __HIP_MEMORY_SCOPE_AGENT);
            tl += __hip_atomic_load(&WSL(ws)[row * CPR + i],  __ATOMIC_RELAXED, __HIP_MEMORY_SCOPE_AGENT);
        }
        solve_params(ts, tl, rmin, spar + 1);   // redundant per-block solve (7x/row, hidden by TLP)
    }
    __syncthreads();

    const float kk = spar[1], invth = spar[2];
    float c[8];
#pragma unroll
    for (int i = 0; i < 8; ++i) c[i] = spar[3 + i];

    // ---- phase C: apply + nontemporal vector stores ----
    floatx4* __restrict__ yr = (floatx4*)out + base;
#pragma unroll
    for (int j = 0; j < 7; ++j) {
        floatx4 o;
        o.x = apply_one(v[j].x, rmin, invth, kk, c);
        o.y = apply_one(v[j].y, rmin, invth, kk, c);
        o.z = apply_one(v[j].z, rmin, invth, kk, c);
        o.w = apply_one(v[j].w, rmin, invth, kk, c);
        __builtin_nontemporal_store(o, yr + j * TPB + tid);
    }
}

// ==================== fallback (non-cooperative) 3-kernel path ====================
__global__ void __launch_bounds__(TPB, 7)
k_phaseA(const float* __restrict__ x, void* __restrict__ ws) {
    const int bid = blockIdx.x, tid = threadIdx.x;
    const int row = bid / CPR, chnk = bid - row * CPR;
    const int wid = tid >> 6, lane = tid & 63;
    const float4* __restrict__ xr = (const float4*)x + (size_t)row * NV4 + (size_t)chnk * CF4;

    float pmin = INFINITY, psum = 0.0f;
#pragma unroll
    for (int j = 0; j < 7; ++j) {
        float4 v = xr[j * TPB + tid];
        pmin = fminf(pmin, fminf(fminf(v.x, v.y), fminf(v.z, v.w)));
        psum += (v.x + v.y) + (v.z + v.w);
    }
    pmin = waveMin(pmin);
    double dsum = waveSumD((double)psum);
    __shared__ float  smin[4];
    __shared__ double sacc[4];
    if (lane == 0) { smin[wid] = pmin; sacc[wid] = dsum; }
    __syncthreads();
    if (tid == 0) {
        WMIN(ws)[bid] = fminf(fminf(smin[0], smin[1]), fminf(smin[2], smin[3]));
        WSUM(ws)[bid] = (sacc[0] + sacc[1]) + (sacc[2] + sacc[3]);
    }
}

__global__ void __launch_bounds__(TPB, 7)
k_phaseB(const float* __restrict__ x, void* __restrict__ ws) {
    const int bid = blockIdx.x, tid = threadIdx.x;
    const int row = bid / CPR, chnk = bid - row * CPR;
    const int wid = tid >> 6, lane = tid & 63;
    float rm = INFINITY;
#pragma unroll
    for (int i = 0; i < CPR; ++i) rm = fminf(rm, WMIN(ws)[row * CPR + i]);
    const float4* __restrict__ xr = (const float4*)x + (size_t)row * NV4 + (size_t)chnk * CF4;

    float psl = 0.0f;
#pragma unroll
    for (int j = 0; j < 7; ++j) {
        float4 v = xr[j * TPB + tid];
        psl += (__logf(v.x - rm + 1e-7f + 1e-7f) + __logf(v.y - rm + 1e-7f + 1e-7f))
             + (__logf(v.z - rm + 1e-7f + 1e-7f) + __logf(v.w - rm + 1e-7f + 1e-7f));
    }
    double dsl = waveSumD((double)psl);
    __shared__ double sacc[4];
    if (lane == 0) sacc[wid] = dsl;
    __syncthreads();
    if (tid == 0) WSL(ws)[bid] = (sacc[0] + sacc[1]) + (sacc[2] + sacc[3]);
}

__global__ void __launch_bounds__(TPB, 7)
k_phaseC(const float* __restrict__ x, float* __restrict__ out, void* __restrict__ ws) {
    const int bid = blockIdx.x, tid = threadIdx.x;
    const int row = bid / CPR, chnk = bid - row * CPR;

    __shared__ float spar[11];
    if (tid == 0) {
        float rm = INFINITY;
        double ts = 0.0, tl = 0.0;
#pragma unroll
        for (int i = 0; i < CPR; ++i) {
            rm = fminf(rm, WMIN(ws)[row * CPR + i]);
            ts += WSUM(ws)[row * CPR + i];
            tl += WSL(ws)[row * CPR + i];
        }
        spar[0] = rm;
        solve_params(ts, tl, rm, spar + 1);
    }
    __syncthreads();
    const float rmin = spar[0], kk = spar[1], invth = spar[2];
    float c[8];
#pragma unroll
    for (int i = 0; i < 8; ++i) c[i] = spar[3 + i];

    const size_t base = (size_t)row * NV4 + (size_t)chnk * CF4;
    const float4* __restrict__ xr = (const float4*)x + base;
    floatx4* __restrict__ yr = (floatx4*)out + base;
#pragma unroll
    for (int j = 0; j < 7; ++j) {
        float4 v = xr[j * TPB + tid];
        floatx4 o;
        o.x = apply_one(v.x, rmin, invth, kk, c);
        o.y = apply_one(v.y, rmin, invth, kk, c);
        o.z = apply_one(v.z, rmin, invth, kk, c);
        o.w = apply_one(v.w, rmin, invth, kk, c);
        __builtin_nontemporal_store(o, yr + j * TPB + tid);
    }
}

extern "C" void kernel_launch(void* const* d_in, const int* in_sizes, int n_in,
                              void* d_out, int out_size, void* d_ws, size_t ws_size,
                              hipStream_t stream) {
    const float* x = (const float*)d_in[0];
    float* out = (float*)d_out;
    void* ws = d_ws;
    const int rows = in_sizes[0] / HW;        // 256
    const int nblk = rows * CPR;              // 1792

    // zero the per-row arrival counters (ws is poisoned 0xAA before every launch)
    hipMemsetAsync((char*)ws + 40960, 0, 2048, stream);

    void* args[] = {(void*)&x, (void*)&out, (void*)&ws};
    hipError_t err = hipLaunchCooperativeKernel((const void*)gamma_sync,
                                                dim3(nblk), dim3(TPB), args, 0, stream);
    if (err != hipSuccess) {
        (void)hipGetLastError();   // clear sticky error; fall back to split pipeline
        k_phaseA<<<dim3(nblk), dim3(TPB), 0, stream>>>(x, ws);
        k_phaseB<<<dim3(nblk), dim3(TPB), 0, stream>>>(x, ws);
        k_phaseC<<<dim3(nblk), dim3(TPB), 0, stream>>>(x, out, ws);
    }
}

// Round 7
// 127.923 us; speedup vs baseline: 2.1274x; 2.1274x over previous
//
#include <hip/hip_runtime.h>
#include <math.h>

// x: (256, 224, 224) f32.
// Grid = 512 blocks x 1024 threads: 2 blocks per row, 2 blocks per CU.
// Each block REDUNDANTLY computes full-row stats (min/sum/sumlog) — no
// cross-block sync of any kind — then applies to its own half-row.
// launch_bounds(1024,8) caps VGPR at 64 so both 16-wave blocks co-reside.
#define HW    50176
#define NV4   12544          // float4 per row;  12544 = 12*1024 + 256
#define HV4   6272           // float4 per half-row; 6272 = 6*1024 + 128
#define TPB   1024
#define ROWS  256

typedef float floatx4 __attribute__((ext_vector_type(4)));

__device__ __forceinline__ float waveMin(float v) {
#pragma unroll
    for (int o = 32; o > 0; o >>= 1) v = fminf(v, __shfl_down(v, o, 64));
    return v;
}
__device__ __forceinline__ double waveSumD(double v) {
#pragma unroll
    for (int o = 32; o > 0; o >>= 1) v += __shfl_down(v, o, 64);
    return v;
}

__device__ __forceinline__ float digamma_f(float x) {
    float r = 0.0f;
#pragma unroll 6
    for (int i = 0; i < 6; ++i) {
        if (x < 6.0f) { r -= __fdividef(1.0f, x); x += 1.0f; }
    }
    float f = __fdividef(1.0f, x * x);
    float ser = f * (1.0f/12.0f - f * (1.0f/120.0f - f * (1.0f/252.0f - f * (1.0f/240.0f - f * (1.0f/132.0f)))));
    return r + logf(x) - 0.5f * __fdividef(1.0f, x) - ser;
}
__device__ __forceinline__ float trigamma_ref(float x) {
    float z = x + 1.0f, zz = z * z;
    float a = 0.2f - __fdividef(1.0f, 7.0f * zz);
    float b = 1.0f - __fdividef(a, zz);
    float c = 1.0f + __fdividef(b, 3.0f * z);
    float d = 1.0f + __fdividef(c, 2.0f * z);
    return __fdividef(d, z) + __fdividef(1.0f, x * x);
}

__global__ void __launch_bounds__(TPB, 8)
gamma_norm2d(const float* __restrict__ x, float* __restrict__ out) {
    const int row  = blockIdx.x >> 1;
    const int half = blockIdx.x & 1;
    const int tid  = threadIdx.x;
    const int wid  = tid >> 6, lane = tid & 63;
    const float4* __restrict__ xr = (const float4*)(x + (size_t)row * HW);

    __shared__ float  smin[16];
    __shared__ double sacc[16];
    __shared__ double ssl[16];
    __shared__ float  sparams[3];   // rmin, k, invth
    __shared__ float  scoef[8];

    // ---- phase A: FULL-row min + raw sum (redundant in both half-blocks) ----
    float pmin = INFINITY, psum = 0.0f;
#pragma unroll
    for (int j = 0; j < 12; ++j) {
        float4 v = xr[j * TPB + tid];
        pmin = fminf(pmin, fminf(fminf(v.x, v.y), fminf(v.z, v.w)));
        psum += (v.x + v.y) + (v.z + v.w);
    }
    if (tid < 256) {                         // tail: 12544 - 12*1024 = 256
        float4 v = xr[12 * TPB + tid];
        pmin = fminf(pmin, fminf(fminf(v.x, v.y), fminf(v.z, v.w)));
        psum += (v.x + v.y) + (v.z + v.w);
    }
    pmin = waveMin(pmin);
    double dsum = waveSumD((double)psum);
    if (lane == 0) { smin[wid] = pmin; sacc[wid] = dsum; }
    __syncthreads();
    if (tid == 0) {
        float mm = smin[0];
        for (int i = 1; i < 16; ++i) mm = fminf(mm, smin[i]);
        sparams[0] = mm;
    }
    __syncthreads();
    const float rmin = sparams[0];

    // ---- phase B: FULL-row sumlog of (x - rmin + 2e-7) (redundant) ----
    float psl = 0.0f;
#pragma unroll
    for (int j = 0; j < 12; ++j) {
        float4 v = xr[j * TPB + tid];
        psl += (__logf(v.x - rmin + 1e-7f + 1e-7f) + __logf(v.y - rmin + 1e-7f + 1e-7f))
             + (__logf(v.z - rmin + 1e-7f + 1e-7f) + __logf(v.w - rmin + 1e-7f + 1e-7f));
    }
    if (tid < 256) {
        float4 v = xr[12 * TPB + tid];
        psl += (__logf(v.x - rmin + 1e-7f + 1e-7f) + __logf(v.y - rmin + 1e-7f + 1e-7f))
             + (__logf(v.z - rmin + 1e-7f + 1e-7f) + __logf(v.w - rmin + 1e-7f + 1e-7f));
    }
    double dsl = waveSumD((double)psl);
    if (lane == 0) ssl[wid] = dsl;
    __syncthreads();

    // ---- per-row scalar solve (thread 0), all-f32 transcendentals ----
    if (tid == 0) {
        double ts = 0.0, tl = 0.0;
        for (int i = 0; i < 16; ++i) { ts += sacc[i]; tl += ssl[i]; }
        ts -= (double)HW * ((double)rmin - 2e-7);   // shift: xm = x - rmin + 2e-7
        const double meand = ts / (double)HW;
        float s = logf((float)meand) - (float)(tl / (double)HW);

        float s3 = s - 3.0f;
        float rt = sqrtf(s3 * s3 + 24.0f * s);
        float k  = __fdividef(3.0f - s + rt, 12.0f * s) + 1e-7f;
#pragma unroll
        for (int it = 0; it < 10; ++it) {
            float nm = logf(k) - digamma_f(k) - s;
            float dn = __fdividef(1.0f, k) - trigamma_ref(k);
            k -= __fdividef(nm, dn);
        }
        if (k < 1e-7f) k = 1e-7f;   // NaN falls through (np.clip semantics)
        if (k > 18.0f) k = 18.0f;

        // Lanczos Gamma(k): accumulator in f64 (cancellation), rest f32
        const double CH[8] = {676.5203681218851, -1259.1392167224028, 771.3234287776531,
                              -176.6150291621406, 12.507343278686905, -0.13857109526572012,
                              9.984369578019572e-06, 1.5056327351493116e-07};
        double acc = 0.9999999999998099;
#pragma unroll
        for (int i = 0; i < 8; ++i) acc += CH[i] / ((double)k + (double)(i + 1));
        float t = k + 7.5f;
        float g = __expf(fmaf(k + 0.5f, __logf(t), -t)) * 2.50662827463f * (float)acc / k;

        float den = g * k;                       // Gamma * k
        scoef[0] = __fdividef(1.0f, den);
#pragma unroll
        for (int j = 1; j < 8; ++j) {
            den *= (k + (float)j);
            scoef[j] = __fdividef(1.0f, den);
        }
        sparams[1] = k;
        sparams[2] = (float)((double)k / meand);   // 1/theta
    }
    __syncthreads();

    const float kk = sparams[1], invth = sparams[2];
    const float c0 = scoef[0], c1 = scoef[1], c2 = scoef[2], c3 = scoef[3];
    const float c4 = scoef[4], c5 = scoef[5], c6 = scoef[6], c7 = scoef[7];

    // ---- phase C: apply OWN half-row only ----
    const float4* __restrict__ xh = xr + (size_t)half * HV4;
    floatx4* __restrict__ yh = (floatx4*)(out + (size_t)row * HW) + (size_t)half * HV4;

#pragma unroll
    for (int j = 0; j < 7; ++j) {                 // 6 full + tail (tid<128)
        if (j < 6 || tid < 128) {
            float4 v = xh[j * TPB + tid];
            float e[4] = {v.x, v.y, v.z, v.w};
            floatx4 o;
#pragma unroll
            for (int q = 0; q < 4; ++q) {
                float xq = (e[q] - rmin + 1e-7f) * invth;
                float p = fmaf(c7, xq, c6);
                p = fmaf(p, xq, c5);
                p = fmaf(p, xq, c4);
                p = fmaf(p, xq, c3);
                p = fmaf(p, xq, c2);
                p = fmaf(p, xq, c1);
                p = fmaf(p, xq, c0);
                float y = __expf(fmaf(kk, __logf(xq), -xq)) * p;
                o[q] = isfinite(y) ? y : 0.0f;
            }
            __builtin_nontemporal_store(o, yh + j * TPB + tid);
        }
    }
}

extern "C" void kernel_launch(void* const* d_in, const int* in_sizes, int n_in,
                              void* d_out, int out_size, void* d_ws, size_t ws_size,
                              hipStream_t stream) {
    const float* x = (const float*)d_in[0];
    float* out = (float*)d_out;
    const int rows = in_sizes[0] / HW;   // 256
    gamma_norm2d<<<dim3(rows * 2), dim3(TPB), 0, stream>>>(x, out);
}